// Round 16
// baseline (50.425 us; speedup 1.0000x reference)
//
#include <hip/hip_runtime.h>
#include <hip/hip_bf16.h>

#define NBS 8
#define NT 32
#define NF 128
#define NDIN 64
#define NNH 8
#define NDOUT 64

typedef __bf16 bf16_t;
typedef __bf16 bf16x8 __attribute__((ext_vector_type(8)));
typedef float f32x4 __attribute__((ext_vector_type(4)));
typedef float f32x2 __attribute__((ext_vector_type(2)));

// ---------------- kernel 1: q/k projection ----------------
// One wave per (t,f): q[b,he] = sum_d X[b,f,t,d] * Wq[t,f,d,he], all 8 b at once.
// Wq/Wk/X each read exactly once from HBM -> ~46MB -> memory-bound, ~6us measured.
__global__ __launch_bounds__(256, 4)
void qk_project_kernel(const float* __restrict__ X,
                       const float* __restrict__ Wq,
                       const float* __restrict__ Wk,
                       float* __restrict__ q_ws,
                       float* __restrict__ k_ws)
{
    __shared__ float lx[4][8][64];
    const int w = threadIdx.x >> 6, lane = threadIdx.x & 63;
    const int gw = blockIdx.x * 4 + w;
    const int t = gw >> 7, f = gw & 127;

    {
        const int b = lane >> 3, d8 = (lane & 7) << 3;
        const float* src = &X[(((size_t)b * NF + f) * NT + t) * NDIN + d8];
        const float4 v0 = *(const float4*)src;
        const float4 v1 = *(const float4*)(src + 4);
        *(float4*)&lx[w][b][d8]     = v0;
        *(float4*)&lx[w][b][d8 + 4] = v1;
    }
    __syncthreads();

    const int dq = lane >> 4, he = lane & 15;
    const float* wq = Wq + ((size_t)t * NF + f) * (NDIN * 16);
    const float* wk = Wk + ((size_t)t * NF + f) * (NDIN * 16);
    float qa[8] = {0,0,0,0,0,0,0,0}, ka[8] = {0,0,0,0,0,0,0,0};
    for (int d0 = 0; d0 < NDIN; d0 += 4) {
        const int d = d0 + dq;
        const float wqv = wq[d * 16 + he];
        const float wkv = wk[d * 16 + he];
#pragma unroll
        for (int b = 0; b < 8; ++b) {
            const float x = lx[w][b][d];
            qa[b] = fmaf(x, wqv, qa[b]);
            ka[b] = fmaf(x, wkv, ka[b]);
        }
    }
#pragma unroll
    for (int b = 0; b < 8; ++b) {
        qa[b] += __shfl_xor(qa[b], 16); qa[b] += __shfl_xor(qa[b], 32);
        ka[b] += __shfl_xor(ka[b], 16); ka[b] += __shfl_xor(ka[b], 32);
    }
#pragma unroll
    for (int bb = 0; bb < 2; ++bb) {
        const int b = dq + bb * 4;
        q_ws[(((size_t)b * NT + t) * 16 + he) * NF + f] = qa[b];
        k_ws[(((size_t)b * NT + t) * 16 + he) * NF + f] = ka[b];
    }
}

// ---------------- kernel 2: attention + output GEMMs ----------------
// Base = r15 (47.6us; xreg/u-reg hoists kept). Round-16 delta: HEAD-PAIR
// ELEMENTWISE FUSION. r15 profile: VALU 27%, MFMA 5.5%, LDS ~4k cy/wave ->
// ~60% issue-idle = per-head serial dependency chain (scores->exp->reduce->
// pack->MFMA->Vscr->MFMA) at 2 waves/SIMD with occupancy grid-capped (r13).
// Fix: compute heads h and h+1 in the SAME inner loops — every instruction
// pair (svA/svB, expA/expB, shuffles) adjacent in one basic block, so the
// in-order wave issues B while A's result is in flight. (r14's region-level
// version was neutral: the scheduler doesn't interleave across regions;
// this does it at the source level.) Peak live regs ~210 < 256 (2 waves/SIMD
// budget, m69); grid=256=1 block/CU so pressure costs no occupancy.
// LAUNCH BOUNDS RULE (r4/r5/r8): 2nd arg >=4 forces the 64-VGPR bucket and
// 300MB of scratch spills; (512,2) is the proven-safe bound.
__global__ __launch_bounds__(512, 2)
void spatial_attn_kernel(const float* __restrict__ X,
                         const float* __restrict__ q_ws,
                         const float* __restrict__ k_ws,
                         const float* __restrict__ Wkey,
                         const float* __restrict__ U,
                         const float* __restrict__ AC,
                         const float* __restrict__ Alpha,
                         const float* __restrict__ Wo,
                         const float* __restrict__ Bias,
                         float* __restrict__ Out)
{
    const int blk  = blockIdx.x;
    const int b    = blk & 7;
    const int t    = blk >> 3;
    const int tid  = threadIdx.x;
    const int w    = tid >> 6;
    const int lane = tid & 63;
    const int cq   = lane & 15;
    const int rq   = lane >> 4;
    const int rt   = w;                // row tile 0..7
    const int frow = 16 * rt + cq;

    // LDS carve: 124928 B (<= 160 KiB; grid caps at 1 block/CU anyway)
    __shared__ __align__(16) unsigned char smem[124928];
    bf16_t* XTs   = (bf16_t*)smem;                        // 16384: d*128 + (((f>>3)^(d&15))<<3) + (f&7)
    float*  kvh   = (float*)(smem + 16384);               //  8192: (h*64+P)*4 + {k0k0,k1k1}
    float*  kvu   = (float*)(smem + 24576);               //  1024: P*4 + {u0u0,u1u1}
    float4 (*qf)[128] = (float4 (*)[128])(smem + 25600);  // 16384: {q0,q1,kf0,kf1}(h,f)
    bf16_t* WTall = (bf16_t*)(smem + 41984);              // 65536: h*4096 + o*64 + (((d>>3)^(o&7))<<3) + (d&7)
    bf16_t (*Vscr)[16][68] = (bf16_t (*)[16][68])(smem + 107520); // 17408

    // ---- stage XT (X^T bf16, XOR-swizzled; r12-verbatim) ----
#pragma unroll
    for (int r = 0; r < 4; ++r) {
        const int idx = tid + r * 512;
        const int f = idx >> 4, d4 = (idx & 15) << 2;
        const float4 v = *(const float4*)&X[(((size_t)b * NF + f) * NT + t) * NDIN + d4];
        float vv[4]; vv[0] = v.x; vv[1] = v.y; vv[2] = v.z; vv[3] = v.w;
#pragma unroll
        for (int i = 0; i < 4; ++i) {
            const int d = d4 + i;
            XTs[d * 128 + (((f >> 3) ^ (d & 15)) << 3) + (f & 7)] = (bf16_t)vv[i];
        }
    }
    // ---- stage qf + kvh: one thread per (h,l), 2 reps (r13-verbatim) ----
#pragma unroll
    for (int r = 0; r < 2; ++r) {
        const int idx = tid + r * 512;
        const int hh = idx >> 7, l = idx & 127;
        const size_t qkb = ((size_t)b * NT + t) * 16;
        const float k0 = k_ws[(qkb + 2 * hh + 0) * NF + l];
        const float k1 = k_ws[(qkb + 2 * hh + 1) * NF + l];
        const float q0 = q_ws[(qkb + 2 * hh + 0) * NF + l];
        const float q1 = q_ws[(qkb + 2 * hh + 1) * NF + l];
        qf[hh][l] = make_float4(q0, q1, k0, k1);
        const int P = l >> 1, c = l & 1;
        const int base = (hh * 64 + P) * 4;
        kvh[base + 0 + c] = k0;
        kvh[base + 2 + c] = k1;
    }
    // ---- stage kvu (h-independent; r13-verbatim) ----
    if (tid < 128) {
        const int l = tid;
        const float2 u01 = *(const float2*)&U[((size_t)t * NF + l) * 2];
        const int P = l >> 1, c = l & 1;
        kvu[P * 4 + 0 + c] = u01.x;
        kvu[P * 4 + 2 + c] = u01.y;
    }
    // ---- stage WTall[h] (bf16, XOR-swizzled; r12-verbatim) ----
#pragma unroll
    for (int rep = 0; rep < 16; ++rep) {
        const int flat = rep * 512 + tid;              // 0..8191
        const int h = flat >> 10, f10 = flat & 1023;
        const int dd = f10 >> 4, o4 = (f10 & 15) << 2;
        const float4 v = *(const float4*)&Wo[((size_t)t * 512 + h * 64 + dd) * NDOUT + o4];
        float vv[4]; vv[0] = v.x; vv[1] = v.y; vv[2] = v.z; vv[3] = v.w;
#pragma unroll
        for (int i = 0; i < 4; ++i) {
            const int o = o4 + i;
            WTall[h * 4096 + o * 64 + (((dd >> 3) ^ (o & 7)) << 3) + (dd & 7)] = (bf16_t)vv[i];
        }
    }

    const float alpha_t = Alpha[t];
    const float wk00 = Wkey[t * 4 + 0], wk01 = Wkey[t * 4 + 1];
    const float wk10 = Wkey[t * 4 + 2], wk11 = Wkey[t * 4 + 3];

    __syncthreads();   // the ONLY barrier

    // ---- hoist 1: XT fragments -> registers (identical for all heads) ----
    bf16x8 xreg[4][4];
#pragma unroll
    for (int kt = 0; kt < 4; ++kt)
#pragma unroll
        for (int ct = 0; ct < 4; ++ct)
            xreg[kt][ct] = *(const bf16x8*)&XTs[(ct * 16 + cq) * 128 + (((kt * 4 + rq) ^ cq) << 3)];

    // ---- hoist 2: u-pairs -> registers (h-independent) ----
    f32x2 u0r[4][4], u1r[4][4];
#pragma unroll
    for (int kt = 0; kt < 4; ++kt)
#pragma unroll
        for (int j2 = 0; j2 < 4; ++j2) {
            const int P = kt * 16 + rq * 4 + j2;
            const float4 up = *(const float4*)&kvu[P * 4];
            u0r[kt][j2] = (f32x2){ up.x, up.y };
            u1r[kt][j2] = (f32x2){ up.z, up.w };
        }

    f32x4 oacc[4] = { {0.f,0.f,0.f,0.f}, {0.f,0.f,0.f,0.f}, {0.f,0.f,0.f,0.f}, {0.f,0.f,0.f,0.f} };

#pragma unroll 1
    for (int h = 0; h < NNH; h += 2) {
        const int hB = h + 1;
        // per-head scalars, both heads up front
        const float4 qqA = qf[h][frow];
        const float4 qqB = qf[hB][frow];
        const float q0A = qqA.x, q1A = qqA.y, kf0A = qqA.z, kf1A = qqA.w;
        const float q0B = qqB.x, q1B = qqB.y, kf0B = qqB.z, kf1B = qqB.w;
        const float v1A = 2.f * alpha_t * AC[t * NNH + h];
        const float v1B = 2.f * alpha_t * AC[t * NNH + hB];
        const float c0A = (q0A - alpha_t) * wk00 + (q1A + v1A) * wk10;
        const float c1A = (q0A - alpha_t) * wk01 + (q1A + v1A) * wk11;
        const float c0B = (q0B - alpha_t) * wk00 + (q1B + v1B) * wk10;
        const float c1B = (q0B - alpha_t) * wk01 + (q1B + v1B) * wk11;

        // ---- scores for BOTH heads, elementwise-interleaved ----
        f32x2 scA[4][4], scB[4][4];
        f32x2 mxA = { -3.0e38f, -3.0e38f }, mxB = { -3.0e38f, -3.0e38f };
#pragma unroll
        for (int kt = 0; kt < 4; ++kt) {
#pragma unroll
            for (int j2 = 0; j2 < 4; ++j2) {
                const int P = kt * 16 + rq * 4 + j2;
                const float4 kpA = *(const float4*)&kvh[(h  * 64 + P) * 4];
                const float4 kpB = *(const float4*)&kvh[(hB * 64 + P) * 4];
                const float l0 = (float)(kt * 32 + rq * 8 + 2 * j2 - frow);
                const f32x2 delp = { l0, l0 + 1.f };
                f32x2 svA = (f32x2){ kpA.x, kpA.y } * q0A + (f32x2){ kpA.z, kpA.w } * q1A
                          + u0r[kt][j2] * kf0A + u1r[kt][j2] * kf1A
                          + (delp * c0A + c1A) * delp;
                f32x2 svB = (f32x2){ kpB.x, kpB.y } * q0B + (f32x2){ kpB.z, kpB.w } * q1B
                          + u0r[kt][j2] * kf0B + u1r[kt][j2] * kf1B
                          + (delp * c0B + c1B) * delp;
                scA[kt][j2] = svA;
                scB[kt][j2] = svB;
                mxA = __builtin_elementwise_max(mxA, svA);
                mxB = __builtin_elementwise_max(mxB, svB);
            }
        }
        float rmA = fmaxf(mxA.x, mxA.y);
        float rmB = fmaxf(mxB.x, mxB.y);
        rmA = fmaxf(rmA, __shfl_xor(rmA, 16));
        rmB = fmaxf(rmB, __shfl_xor(rmB, 16));
        rmA = fmaxf(rmA, __shfl_xor(rmA, 32));
        rmB = fmaxf(rmB, __shfl_xor(rmB, 32));
        f32x2 s2A = { 0.f, 0.f }, s2B = { 0.f, 0.f };
#pragma unroll
        for (int kt = 0; kt < 4; ++kt)
#pragma unroll
            for (int j2 = 0; j2 < 4; ++j2) {
                const f32x2 svA = scA[kt][j2];
                const f32x2 svB = scB[kt][j2];
                const f32x2 eA = { __expf(svA.x - rmA), __expf(svA.y - rmA) };
                const f32x2 eB = { __expf(svB.x - rmB), __expf(svB.y - rmB) };
                s2A += eA; s2B += eB;
                scA[kt][j2] = eA;
                scB[kt][j2] = eB;
            }
        float sumA = s2A.x + s2A.y;
        float sumB = s2B.x + s2B.y;
        sumA += __shfl_xor(sumA, 16);
        sumB += __shfl_xor(sumB, 16);
        sumA += __shfl_xor(sumA, 32);
        sumB += __shfl_xor(sumB, 32);
        const float rinvA = 1.f / sumA;
        const float rinvB = 1.f / sumB;

        // ---- pack BOTH heads' P fragments ----
        bf16x8 pfA[4], pfB[4];
#pragma unroll
        for (int kt = 0; kt < 4; ++kt) {
#pragma unroll
            for (int j2 = 0; j2 < 4; ++j2) {
                const f32x2 eA = scA[kt][j2];
                const f32x2 eB = scB[kt][j2];
                pfA[kt][2 * j2 + 0] = (bf16_t)(eA.x * rinvA);
                pfA[kt][2 * j2 + 1] = (bf16_t)(eA.y * rinvA);
                pfB[kt][2 * j2 + 0] = (bf16_t)(eB.x * rinvB);
                pfB[kt][2 * j2 + 1] = (bf16_t)(eB.y * rinvB);
            }
        }

        // ---- GEMM1+Vscr+GEMM2, head A then head B (r15-verbatim bodies) ----
#pragma unroll
        for (int pp = 0; pp < 2; ++pp) {
            const bf16x8* pf = pp ? pfB : pfA;
            const int hn = pp ? hB : h;
            f32x4 vacc[4] = { {0.f,0.f,0.f,0.f}, {0.f,0.f,0.f,0.f}, {0.f,0.f,0.f,0.f}, {0.f,0.f,0.f,0.f} };
#pragma unroll
            for (int kt = 0; kt < 4; ++kt)
#pragma unroll
                for (int ct = 0; ct < 4; ++ct)
                    vacc[ct] = __builtin_amdgcn_mfma_f32_16x16x32_bf16(pf[kt], xreg[kt][ct], vacc[ct], 0, 0, 0);
#pragma unroll
            for (int ct = 0; ct < 4; ++ct)
#pragma unroll
                for (int rr = 0; rr < 4; ++rr)
                    Vscr[w][rq * 4 + rr][ct * 16 + cq] = (bf16_t)vacc[ct][rr];
#pragma unroll
            for (int kt = 0; kt < 2; ++kt) {
                const bf16x8 a = *(const bf16x8*)&Vscr[w][cq][kt * 32 + rq * 8];
#pragma unroll
                for (int ct = 0; ct < 4; ++ct) {
                    const bf16x8 bw = *(const bf16x8*)&WTall[hn * 4096 + (ct * 16 + cq) * 64 + (((kt * 4 + rq) ^ (cq & 7)) << 3)];
                    oacc[ct] = __builtin_amdgcn_mfma_f32_16x16x32_bf16(a, bw, oacc[ct], 0, 0, 0);
                }
            }
        }
    }

    // ---- epilogue: Out = oacc + bias (all 8 heads complete per wave) ----
#pragma unroll
    for (int ct = 0; ct < 4; ++ct) {
#pragma unroll
        for (int rr = 0; rr < 4; ++rr) {
            const int f = 16 * rt + rq * 4 + rr;
            const int o = ct * 16 + cq;
            Out[(((size_t)b * NF + f) * NT + t) * NDOUT + o] =
                oacc[ct][rr] + Bias[((size_t)f * NT + t) * NDOUT + o];
        }
    }
}

extern "C" void kernel_launch(void* const* d_in, const int* in_sizes, int n_in,
                              void* d_out, int out_size, void* d_ws, size_t ws_size,
                              hipStream_t stream) {
    (void)in_sizes; (void)n_in; (void)ws_size; (void)out_size;
    const float* X    = (const float*)d_in[0];
    const float* Wq   = (const float*)d_in[1];
    const float* Wk   = (const float*)d_in[2];
    const float* Wkey = (const float*)d_in[3];
    const float* U    = (const float*)d_in[4];
    const float* AC   = (const float*)d_in[5];
    const float* Al   = (const float*)d_in[6];
    // d_in[7] = R is analytic (delta^2, delta), folded into score formula
    const float* Wo   = (const float*)d_in[8];
    const float* Bias = (const float*)d_in[9];

    float* q_ws = (float*)d_ws;                       // 2 MB
    float* k_ws = q_ws + (size_t)NBS * NT * 16 * NF;  // 2 MB

    qk_project_kernel<<<dim3(NT * NF / 4), dim3(256), 0, stream>>>(X, Wq, Wk, q_ws, k_ws);
    spatial_attn_kernel<<<dim3(NBS * NT), dim3(512), 0, stream>>>(
        X, q_ws, k_ws, Wkey, U, AC, Al, Wo, Bias, (float*)d_out);
}

// Round 17
// 47.535 us; speedup vs baseline: 1.0608x; 1.0608x over previous
//
#include <hip/hip_runtime.h>
#include <hip/hip_bf16.h>

#define NBS 8
#define NT 32
#define NF 128
#define NDIN 64
#define NNH 8
#define NDOUT 64

typedef __bf16 bf16_t;
typedef __bf16 bf16x8 __attribute__((ext_vector_type(8)));
typedef float f32x4 __attribute__((ext_vector_type(4)));
typedef float f32x2 __attribute__((ext_vector_type(2)));

// ---------------- kernel 1: q/k projection ----------------
// One wave per (t,f): q[b,he] = sum_d X[b,f,t,d] * Wq[t,f,d,he], all 8 b at once.
// Wq/Wk/X each read exactly once from HBM -> ~46MB -> memory-bound, ~6us measured.
__global__ __launch_bounds__(256, 4)
void qk_project_kernel(const float* __restrict__ X,
                       const float* __restrict__ Wq,
                       const float* __restrict__ Wk,
                       float* __restrict__ q_ws,
                       float* __restrict__ k_ws)
{
    __shared__ float lx[4][8][64];
    const int w = threadIdx.x >> 6, lane = threadIdx.x & 63;
    const int gw = blockIdx.x * 4 + w;
    const int t = gw >> 7, f = gw & 127;

    {
        const int b = lane >> 3, d8 = (lane & 7) << 3;
        const float* src = &X[(((size_t)b * NF + f) * NT + t) * NDIN + d8];
        const float4 v0 = *(const float4*)src;
        const float4 v1 = *(const float4*)(src + 4);
        *(float4*)&lx[w][b][d8]     = v0;
        *(float4*)&lx[w][b][d8 + 4] = v1;
    }
    __syncthreads();

    const int dq = lane >> 4, he = lane & 15;
    const float* wq = Wq + ((size_t)t * NF + f) * (NDIN * 16);
    const float* wk = Wk + ((size_t)t * NF + f) * (NDIN * 16);
    float qa[8] = {0,0,0,0,0,0,0,0}, ka[8] = {0,0,0,0,0,0,0,0};
    for (int d0 = 0; d0 < NDIN; d0 += 4) {
        const int d = d0 + dq;
        const float wqv = wq[d * 16 + he];
        const float wkv = wk[d * 16 + he];
#pragma unroll
        for (int b = 0; b < 8; ++b) {
            const float x = lx[w][b][d];
            qa[b] = fmaf(x, wqv, qa[b]);
            ka[b] = fmaf(x, wkv, ka[b]);
        }
    }
#pragma unroll
    for (int b = 0; b < 8; ++b) {
        qa[b] += __shfl_xor(qa[b], 16); qa[b] += __shfl_xor(qa[b], 32);
        ka[b] += __shfl_xor(ka[b], 16); ka[b] += __shfl_xor(ka[b], 32);
    }
#pragma unroll
    for (int bb = 0; bb < 2; ++bb) {
        const int b = dq + bb * 4;
        q_ws[(((size_t)b * NT + t) * 16 + he) * NF + f] = qa[b];
        k_ws[(((size_t)b * NT + t) * 16 + he) * NF + f] = ka[b];
    }
}

// ---------------- kernel 2: attention + output GEMMs ----------------
// Base = r15 (47.6us best; r16 head-pair fusion spilled at the 128-VGPR
// allocator ceiling and regressed -> reverted). Round-17 delta: C01
// PRECOMPUTE — the per-head chain head was {global AC load (~200-900cy) +
// 10-op v1/c0/c1 serial chain} feeding every score. Staging threads now
// precompute hc[h][l] = {c0,c1} (8KB LDS); the loop reads one ds_read_b64.
// Register-budget-neutral (r16 lesson: anything that widens live state
// past 128 spills). alpha/wk scalar loads hoisted above staging.
// LAUNCH BOUNDS RULE (r4/r5/r8): 2nd arg >=4 forces the 64-VGPR bucket and
// 300MB of scratch spills; (512,2) is the proven-safe bound.
__global__ __launch_bounds__(512, 2)
void spatial_attn_kernel(const float* __restrict__ X,
                         const float* __restrict__ q_ws,
                         const float* __restrict__ k_ws,
                         const float* __restrict__ Wkey,
                         const float* __restrict__ U,
                         const float* __restrict__ AC,
                         const float* __restrict__ Alpha,
                         const float* __restrict__ Wo,
                         const float* __restrict__ Bias,
                         float* __restrict__ Out)
{
    const int blk  = blockIdx.x;
    const int b    = blk & 7;
    const int t    = blk >> 3;
    const int tid  = threadIdx.x;
    const int w    = tid >> 6;
    const int lane = tid & 63;
    const int cq   = lane & 15;
    const int rq   = lane >> 4;
    const int rt   = w;                // row tile 0..7
    const int frow = 16 * rt + cq;

    // LDS carve: 133120 B (<= 160 KiB; grid caps at 1 block/CU anyway)
    __shared__ __align__(16) unsigned char smem[133120];
    bf16_t* XTs   = (bf16_t*)smem;                        // 16384: d*128 + (((f>>3)^(d&15))<<3) + (f&7)
    float*  kvh   = (float*)(smem + 16384);               //  8192: (h*64+P)*4 + {k0k0,k1k1}
    float*  kvu   = (float*)(smem + 24576);               //  1024: P*4 + {u0u0,u1u1}
    float2 (*hc)[128] = (float2 (*)[128])(smem + 25600);  //  8192: {c0,c1}(h,f)
    float4 (*qf)[128] = (float4 (*)[128])(smem + 33792);  // 16384: {q0,q1,kf0,kf1}(h,f)
    bf16_t* WTall = (bf16_t*)(smem + 50176);              // 65536: h*4096 + o*64 + (((d>>3)^(o&7))<<3) + (d&7)
    bf16_t (*Vscr)[16][68] = (bf16_t (*)[16][68])(smem + 115712); // 17408

    // ---- uniform scalars FIRST (staging needs them for hc) ----
    const float alpha_t = Alpha[t];
    const float wk00 = Wkey[t * 4 + 0], wk01 = Wkey[t * 4 + 1];
    const float wk10 = Wkey[t * 4 + 2], wk11 = Wkey[t * 4 + 3];

    // ---- stage XT (X^T bf16, XOR-swizzled; r12-verbatim) ----
#pragma unroll
    for (int r = 0; r < 4; ++r) {
        const int idx = tid + r * 512;
        const int f = idx >> 4, d4 = (idx & 15) << 2;
        const float4 v = *(const float4*)&X[(((size_t)b * NF + f) * NT + t) * NDIN + d4];
        float vv[4]; vv[0] = v.x; vv[1] = v.y; vv[2] = v.z; vv[3] = v.w;
#pragma unroll
        for (int i = 0; i < 4; ++i) {
            const int d = d4 + i;
            XTs[d * 128 + (((f >> 3) ^ (d & 15)) << 3) + (f & 7)] = (bf16_t)vv[i];
        }
    }
    // ---- stage qf + kvh + hc: one thread per (h,l), 2 reps ----
#pragma unroll
    for (int r = 0; r < 2; ++r) {
        const int idx = tid + r * 512;
        const int hh = idx >> 7, l = idx & 127;
        const size_t qkb = ((size_t)b * NT + t) * 16;
        const float k0 = k_ws[(qkb + 2 * hh + 0) * NF + l];
        const float k1 = k_ws[(qkb + 2 * hh + 1) * NF + l];
        const float q0 = q_ws[(qkb + 2 * hh + 0) * NF + l];
        const float q1 = q_ws[(qkb + 2 * hh + 1) * NF + l];
        qf[hh][l] = make_float4(q0, q1, k0, k1);
        const int P = l >> 1, c = l & 1;
        const int base = (hh * 64 + P) * 4;
        kvh[base + 0 + c] = k0;
        kvh[base + 2 + c] = k1;
        // c01 precompute: the per-head score constants for row l
        const float v1 = 2.f * alpha_t * AC[t * NNH + hh];
        const float c0 = (q0 - alpha_t) * wk00 + (q1 + v1) * wk10;
        const float c1 = (q0 - alpha_t) * wk01 + (q1 + v1) * wk11;
        hc[hh][l] = make_float2(c0, c1);
    }
    // ---- stage kvu (h-independent; r13-verbatim) ----
    if (tid < 128) {
        const int l = tid;
        const float2 u01 = *(const float2*)&U[((size_t)t * NF + l) * 2];
        const int P = l >> 1, c = l & 1;
        kvu[P * 4 + 0 + c] = u01.x;
        kvu[P * 4 + 2 + c] = u01.y;
    }
    // ---- stage WTall[h] (bf16, XOR-swizzled; r12-verbatim) ----
#pragma unroll
    for (int rep = 0; rep < 16; ++rep) {
        const int flat = rep * 512 + tid;              // 0..8191
        const int h = flat >> 10, f10 = flat & 1023;
        const int dd = f10 >> 4, o4 = (f10 & 15) << 2;
        const float4 v = *(const float4*)&Wo[((size_t)t * 512 + h * 64 + dd) * NDOUT + o4];
        float vv[4]; vv[0] = v.x; vv[1] = v.y; vv[2] = v.z; vv[3] = v.w;
#pragma unroll
        for (int i = 0; i < 4; ++i) {
            const int o = o4 + i;
            WTall[h * 4096 + o * 64 + (((dd >> 3) ^ (o & 7)) << 3) + (dd & 7)] = (bf16_t)vv[i];
        }
    }

    __syncthreads();   // the ONLY barrier

    // ---- hoist 1: XT fragments -> registers (identical for all heads) ----
    bf16x8 xreg[4][4];
#pragma unroll
    for (int kt = 0; kt < 4; ++kt)
#pragma unroll
        for (int ct = 0; ct < 4; ++ct)
            xreg[kt][ct] = *(const bf16x8*)&XTs[(ct * 16 + cq) * 128 + (((kt * 4 + rq) ^ cq) << 3)];

    // ---- hoist 2: u-pairs -> registers (h-independent) ----
    f32x2 u0r[4][4], u1r[4][4];
#pragma unroll
    for (int kt = 0; kt < 4; ++kt)
#pragma unroll
        for (int j2 = 0; j2 < 4; ++j2) {
            const int P = kt * 16 + rq * 4 + j2;
            const float4 up = *(const float4*)&kvu[P * 4];
            u0r[kt][j2] = (f32x2){ up.x, up.y };
            u1r[kt][j2] = (f32x2){ up.z, up.w };
        }

    f32x4 oacc[4] = { {0.f,0.f,0.f,0.f}, {0.f,0.f,0.f,0.f}, {0.f,0.f,0.f,0.f}, {0.f,0.f,0.f,0.f} };

#pragma unroll 1
    for (int h = 0; h < NNH; ++h) {
        const float4 qq = qf[h][frow];             // {q0,q1,kf0,kf1}
        const float2 cc = hc[h][frow];             // {c0,c1} precomputed
        const float q0 = qq.x, q1 = qq.y, kf0 = qq.z, kf1 = qq.w;
        const float c0 = cc.x, c1 = cc.y;

        // ---- scores: k-pair from LDS (16 b128), u from registers ----
        f32x2 sc2[4][4];
        f32x2 mx2 = { -3.0e38f, -3.0e38f };
#pragma unroll
        for (int kt = 0; kt < 4; ++kt) {
#pragma unroll
            for (int j2 = 0; j2 < 4; ++j2) {
                const int P = kt * 16 + rq * 4 + j2;
                const float4 kp = *(const float4*)&kvh[(h * 64 + P) * 4];
                const f32x2 k0p = { kp.x, kp.y };
                const f32x2 k1p = { kp.z, kp.w };
                const float l0 = (float)(kt * 32 + rq * 8 + 2 * j2 - frow);
                const f32x2 delp = { l0, l0 + 1.f };
                f32x2 sv = k0p * q0 + k1p * q1 + u0r[kt][j2] * kf0 + u1r[kt][j2] * kf1
                         + (delp * c0 + c1) * delp;
                sc2[kt][j2] = sv;
                mx2 = __builtin_elementwise_max(mx2, sv);
            }
        }
        float rowmax = fmaxf(mx2.x, mx2.y);
        rowmax = fmaxf(rowmax, __shfl_xor(rowmax, 16));
        rowmax = fmaxf(rowmax, __shfl_xor(rowmax, 32));
        f32x2 s2 = { 0.f, 0.f };
#pragma unroll
        for (int kt = 0; kt < 4; ++kt)
#pragma unroll
            for (int j2 = 0; j2 < 4; ++j2) {
                f32x2 sv = sc2[kt][j2];
                const f32x2 e = { __expf(sv.x - rowmax), __expf(sv.y - rowmax) };
                s2 += e;
                sc2[kt][j2] = e;
            }
        float sum = s2.x + s2.y;
        sum += __shfl_xor(sum, 16);
        sum += __shfl_xor(sum, 32);
        const float rinv = 1.f / sum;

        // ---- GEMM1: V[16x64] = P[16x128] @ X[128x64]; B-frags from xreg ----
        f32x4 vacc[4] = { {0.f,0.f,0.f,0.f}, {0.f,0.f,0.f,0.f}, {0.f,0.f,0.f,0.f}, {0.f,0.f,0.f,0.f} };
#pragma unroll
        for (int kt = 0; kt < 4; ++kt) {
            bf16x8 pf;
#pragma unroll
            for (int j2 = 0; j2 < 4; ++j2) {
                const f32x2 e = sc2[kt][j2];
                pf[2 * j2 + 0] = (bf16_t)(e.x * rinv);
                pf[2 * j2 + 1] = (bf16_t)(e.y * rinv);
            }
#pragma unroll
            for (int ct = 0; ct < 4; ++ct)
                vacc[ct] = __builtin_amdgcn_mfma_f32_16x16x32_bf16(pf, xreg[kt][ct], vacc[ct], 0, 0, 0);
        }
        // V C-frags -> private wave scratch (intra-wave dep only, no barrier)
#pragma unroll
        for (int ct = 0; ct < 4; ++ct)
#pragma unroll
            for (int rr = 0; rr < 4; ++rr)
                Vscr[w][rq * 4 + rr][ct * 16 + cq] = (bf16_t)vacc[ct][rr];

        // ---- GEMM2: oacc += V[16x64] @ W_h[64x64] ----
#pragma unroll
        for (int kt = 0; kt < 2; ++kt) {
            const bf16x8 a = *(const bf16x8*)&Vscr[w][cq][kt * 32 + rq * 8];
#pragma unroll
            for (int ct = 0; ct < 4; ++ct) {
                const bf16x8 bw = *(const bf16x8*)&WTall[h * 4096 + (ct * 16 + cq) * 64 + (((kt * 4 + rq) ^ (cq & 7)) << 3)];
                oacc[ct] = __builtin_amdgcn_mfma_f32_16x16x32_bf16(a, bw, oacc[ct], 0, 0, 0);
            }
        }
    }

    // ---- epilogue: Out = oacc + bias (all 8 heads complete per wave) ----
#pragma unroll
    for (int ct = 0; ct < 4; ++ct) {
#pragma unroll
        for (int rr = 0; rr < 4; ++rr) {
            const int f = 16 * rt + rq * 4 + rr;
            const int o = ct * 16 + cq;
            Out[(((size_t)b * NF + f) * NT + t) * NDOUT + o] =
                oacc[ct][rr] + Bias[((size_t)f * NT + t) * NDOUT + o];
        }
    }
}

extern "C" void kernel_launch(void* const* d_in, const int* in_sizes, int n_in,
                              void* d_out, int out_size, void* d_ws, size_t ws_size,
                              hipStream_t stream) {
    (void)in_sizes; (void)n_in; (void)ws_size; (void)out_size;
    const float* X    = (const float*)d_in[0];
    const float* Wq   = (const float*)d_in[1];
    const float* Wk   = (const float*)d_in[2];
    const float* Wkey = (const float*)d_in[3];
    const float* U    = (const float*)d_in[4];
    const float* AC   = (const float*)d_in[5];
    const float* Al   = (const float*)d_in[6];
    // d_in[7] = R is analytic (delta^2, delta), folded into score formula
    const float* Wo   = (const float*)d_in[8];
    const float* Bias = (const float*)d_in[9];

    float* q_ws = (float*)d_ws;                       // 2 MB
    float* k_ws = q_ws + (size_t)NBS * NT * 16 * NF;  // 2 MB

    qk_project_kernel<<<dim3(NT * NF / 4), dim3(256), 0, stream>>>(X, Wq, Wk, q_ws, k_ws);
    spatial_attn_kernel<<<dim3(NBS * NT), dim3(512), 0, stream>>>(
        X, q_ws, k_ws, Wkey, U, AC, Al, Wo, Bias, (float*)d_out);
}

// Round 18
// 45.336 us; speedup vs baseline: 1.1123x; 1.0485x over previous
//
#include <hip/hip_runtime.h>
#include <hip/hip_bf16.h>

#define NBS 8
#define NT 32
#define NF 128
#define NDIN 64
#define NNH 8
#define NDOUT 64

typedef __bf16 bf16_t;
typedef __bf16 bf16x8 __attribute__((ext_vector_type(8)));
typedef float f32x4 __attribute__((ext_vector_type(4)));
typedef float f32x2 __attribute__((ext_vector_type(2)));

// ---------------- kernel 1: q/k projection ----------------
// One wave per (t,f): q[b,he] = sum_d X[b,f,t,d] * Wq[t,f,d,he], all 8 b at once.
// Wq/Wk/X each read exactly once from HBM -> ~46MB -> memory-bound, ~6us measured.
__global__ __launch_bounds__(256, 4)
void qk_project_kernel(const float* __restrict__ X,
                       const float* __restrict__ Wq,
                       const float* __restrict__ Wk,
                       float* __restrict__ q_ws,
                       float* __restrict__ k_ws)
{
    __shared__ float lx[4][8][64];
    const int w = threadIdx.x >> 6, lane = threadIdx.x & 63;
    const int gw = blockIdx.x * 4 + w;
    const int t = gw >> 7, f = gw & 127;

    {
        const int b = lane >> 3, d8 = (lane & 7) << 3;
        const float* src = &X[(((size_t)b * NF + f) * NT + t) * NDIN + d8];
        const float4 v0 = *(const float4*)src;
        const float4 v1 = *(const float4*)(src + 4);
        *(float4*)&lx[w][b][d8]     = v0;
        *(float4*)&lx[w][b][d8 + 4] = v1;
    }
    __syncthreads();

    const int dq = lane >> 4, he = lane & 15;
    const float* wq = Wq + ((size_t)t * NF + f) * (NDIN * 16);
    const float* wk = Wk + ((size_t)t * NF + f) * (NDIN * 16);
    float qa[8] = {0,0,0,0,0,0,0,0}, ka[8] = {0,0,0,0,0,0,0,0};
    for (int d0 = 0; d0 < NDIN; d0 += 4) {
        const int d = d0 + dq;
        const float wqv = wq[d * 16 + he];
        const float wkv = wk[d * 16 + he];
#pragma unroll
        for (int b = 0; b < 8; ++b) {
            const float x = lx[w][b][d];
            qa[b] = fmaf(x, wqv, qa[b]);
            ka[b] = fmaf(x, wkv, ka[b]);
        }
    }
#pragma unroll
    for (int b = 0; b < 8; ++b) {
        qa[b] += __shfl_xor(qa[b], 16); qa[b] += __shfl_xor(qa[b], 32);
        ka[b] += __shfl_xor(ka[b], 16); ka[b] += __shfl_xor(ka[b], 32);
    }
#pragma unroll
    for (int bb = 0; bb < 2; ++bb) {
        const int b = dq + bb * 4;
        q_ws[(((size_t)b * NT + t) * 16 + he) * NF + f] = qa[b];
        k_ws[(((size_t)b * NT + t) * 16 + he) * NF + f] = ka[b];
    }
}

// ---------------- kernel 2: attention + output GEMMs ----------------
// Base = r17 (47.5us). Round-18 delta: SEPARATE __shared__ ARRAYS instead of
// one byte-carved smem[]. Theory: with a single carved array, every LDS
// buffer is smem+runtime_offset -> the compiler cannot prove Vscr STORES
// (inside the h-loop) don't alias kvh/qf/WTall LOADS of the next head, so
// it cannot hoist/pipeline LDS ops across heads and serializes the chain
// behind conservative lgkmcnt waits. Distinct arrays = distinct objects =
// provably non-aliasing -> scheduler may prefetch next-head operands over
// this head's Vscr round-trip. Everything else r17-verbatim (c01 table,
// xreg/u-reg hoists, swizzled XT/WTall, pk-f32 scores, ONE barrier).
// LAUNCH BOUNDS RULE (r4/r5/r8): 2nd arg >=4 -> 64-VGPR bucket + spills;
// (512,2) proven safe. 128-VGPR allocator ceiling at 512thr (r16).
__global__ __launch_bounds__(512, 2)
void spatial_attn_kernel(const float* __restrict__ X,
                         const float* __restrict__ q_ws,
                         const float* __restrict__ k_ws,
                         const float* __restrict__ Wkey,
                         const float* __restrict__ U,
                         const float* __restrict__ AC,
                         const float* __restrict__ Alpha,
                         const float* __restrict__ Wo,
                         const float* __restrict__ Bias,
                         float* __restrict__ Out)
{
    const int blk  = blockIdx.x;
    const int b    = blk & 7;
    const int t    = blk >> 3;
    const int tid  = threadIdx.x;
    const int w    = tid >> 6;
    const int lane = tid & 63;
    const int cq   = lane & 15;
    const int rq   = lane >> 4;
    const int rt   = w;                // row tile 0..7
    const int frow = 16 * rt + cq;

    // Distinct LDS objects (133120 B total) — non-aliasing by construction.
    __shared__ bf16_t XTs[8192];        // 16384B: d*128 + (((f>>3)^(d&15))<<3) + (f&7)
    __shared__ float  kvh[2048];        //  8192B: (h*64+P)*4 + {k0k0,k1k1}
    __shared__ float  kvu[256];         //  1024B: P*4 + {u0u0,u1u1}
    __shared__ float2 hc[NNH][128];     //  8192B: {c0,c1}(h,f)
    __shared__ float4 qf[NNH][128];     // 16384B: {q0,q1,kf0,kf1}(h,f)
    __shared__ bf16_t WTall[32768];     // 65536B: h*4096 + o*64 + (((d>>3)^(o&7))<<3) + (d&7)
    __shared__ bf16_t Vscr[8][16][68];  // 17408B

    // ---- uniform scalars FIRST (staging needs them for hc) ----
    const float alpha_t = Alpha[t];
    const float wk00 = Wkey[t * 4 + 0], wk01 = Wkey[t * 4 + 1];
    const float wk10 = Wkey[t * 4 + 2], wk11 = Wkey[t * 4 + 3];

    // ---- stage XT (X^T bf16, XOR-swizzled; r12-verbatim) ----
#pragma unroll
    for (int r = 0; r < 4; ++r) {
        const int idx = tid + r * 512;
        const int f = idx >> 4, d4 = (idx & 15) << 2;
        const float4 v = *(const float4*)&X[(((size_t)b * NF + f) * NT + t) * NDIN + d4];
        float vv[4]; vv[0] = v.x; vv[1] = v.y; vv[2] = v.z; vv[3] = v.w;
#pragma unroll
        for (int i = 0; i < 4; ++i) {
            const int d = d4 + i;
            XTs[d * 128 + (((f >> 3) ^ (d & 15)) << 3) + (f & 7)] = (bf16_t)vv[i];
        }
    }
    // ---- stage qf + kvh + hc: one thread per (h,l), 2 reps ----
#pragma unroll
    for (int r = 0; r < 2; ++r) {
        const int idx = tid + r * 512;
        const int hh = idx >> 7, l = idx & 127;
        const size_t qkb = ((size_t)b * NT + t) * 16;
        const float k0 = k_ws[(qkb + 2 * hh + 0) * NF + l];
        const float k1 = k_ws[(qkb + 2 * hh + 1) * NF + l];
        const float q0 = q_ws[(qkb + 2 * hh + 0) * NF + l];
        const float q1 = q_ws[(qkb + 2 * hh + 1) * NF + l];
        qf[hh][l] = make_float4(q0, q1, k0, k1);
        const int P = l >> 1, c = l & 1;
        const int base = (hh * 64 + P) * 4;
        kvh[base + 0 + c] = k0;
        kvh[base + 2 + c] = k1;
        const float v1 = 2.f * alpha_t * AC[t * NNH + hh];
        const float c0 = (q0 - alpha_t) * wk00 + (q1 + v1) * wk10;
        const float c1 = (q0 - alpha_t) * wk01 + (q1 + v1) * wk11;
        hc[hh][l] = make_float2(c0, c1);
    }
    // ---- stage kvu (h-independent) ----
    if (tid < 128) {
        const int l = tid;
        const float2 u01 = *(const float2*)&U[((size_t)t * NF + l) * 2];
        const int P = l >> 1, c = l & 1;
        kvu[P * 4 + 0 + c] = u01.x;
        kvu[P * 4 + 2 + c] = u01.y;
    }
    // ---- stage WTall[h] (bf16, XOR-swizzled; r12-verbatim) ----
#pragma unroll
    for (int rep = 0; rep < 16; ++rep) {
        const int flat = rep * 512 + tid;              // 0..8191
        const int h = flat >> 10, f10 = flat & 1023;
        const int dd = f10 >> 4, o4 = (f10 & 15) << 2;
        const float4 v = *(const float4*)&Wo[((size_t)t * 512 + h * 64 + dd) * NDOUT + o4];
        float vv[4]; vv[0] = v.x; vv[1] = v.y; vv[2] = v.z; vv[3] = v.w;
#pragma unroll
        for (int i = 0; i < 4; ++i) {
            const int o = o4 + i;
            WTall[h * 4096 + o * 64 + (((dd >> 3) ^ (o & 7)) << 3) + (dd & 7)] = (bf16_t)vv[i];
        }
    }

    __syncthreads();   // the ONLY barrier

    // ---- hoist 1: XT fragments -> registers (identical for all heads) ----
    bf16x8 xreg[4][4];
#pragma unroll
    for (int kt = 0; kt < 4; ++kt)
#pragma unroll
        for (int ct = 0; ct < 4; ++ct)
            xreg[kt][ct] = *(const bf16x8*)&XTs[(ct * 16 + cq) * 128 + (((kt * 4 + rq) ^ cq) << 3)];

    // ---- hoist 2: u-pairs -> registers (h-independent) ----
    f32x2 u0r[4][4], u1r[4][4];
#pragma unroll
    for (int kt = 0; kt < 4; ++kt)
#pragma unroll
        for (int j2 = 0; j2 < 4; ++j2) {
            const int P = kt * 16 + rq * 4 + j2;
            const float4 up = *(const float4*)&kvu[P * 4];
            u0r[kt][j2] = (f32x2){ up.x, up.y };
            u1r[kt][j2] = (f32x2){ up.z, up.w };
        }

    f32x4 oacc[4] = { {0.f,0.f,0.f,0.f}, {0.f,0.f,0.f,0.f}, {0.f,0.f,0.f,0.f}, {0.f,0.f,0.f,0.f} };

#pragma unroll 1
    for (int h = 0; h < NNH; ++h) {
        const float4 qq = qf[h][frow];             // {q0,q1,kf0,kf1}
        const float2 cc = hc[h][frow];             // {c0,c1} precomputed
        const float q0 = qq.x, q1 = qq.y, kf0 = qq.z, kf1 = qq.w;
        const float c0 = cc.x, c1 = cc.y;

        // ---- scores: k-pair from LDS (16 b128), u from registers ----
        f32x2 sc2[4][4];
        f32x2 mx2 = { -3.0e38f, -3.0e38f };
#pragma unroll
        for (int kt = 0; kt < 4; ++kt) {
#pragma unroll
            for (int j2 = 0; j2 < 4; ++j2) {
                const int P = kt * 16 + rq * 4 + j2;
                const float4 kp = *(const float4*)&kvh[(h * 64 + P) * 4];
                const f32x2 k0p = { kp.x, kp.y };
                const f32x2 k1p = { kp.z, kp.w };
                const float l0 = (float)(kt * 32 + rq * 8 + 2 * j2 - frow);
                const f32x2 delp = { l0, l0 + 1.f };
                f32x2 sv = k0p * q0 + k1p * q1 + u0r[kt][j2] * kf0 + u1r[kt][j2] * kf1
                         + (delp * c0 + c1) * delp;
                sc2[kt][j2] = sv;
                mx2 = __builtin_elementwise_max(mx2, sv);
            }
        }
        float rowmax = fmaxf(mx2.x, mx2.y);
        rowmax = fmaxf(rowmax, __shfl_xor(rowmax, 16));
        rowmax = fmaxf(rowmax, __shfl_xor(rowmax, 32));
        f32x2 s2 = { 0.f, 0.f };
#pragma unroll
        for (int kt = 0; kt < 4; ++kt)
#pragma unroll
            for (int j2 = 0; j2 < 4; ++j2) {
                f32x2 sv = sc2[kt][j2];
                const f32x2 e = { __expf(sv.x - rowmax), __expf(sv.y - rowmax) };
                s2 += e;
                sc2[kt][j2] = e;
            }
        float sum = s2.x + s2.y;
        sum += __shfl_xor(sum, 16);
        sum += __shfl_xor(sum, 32);
        const float rinv = 1.f / sum;

        // ---- GEMM1: V[16x64] = P[16x128] @ X[128x64]; B-frags from xreg ----
        f32x4 vacc[4] = { {0.f,0.f,0.f,0.f}, {0.f,0.f,0.f,0.f}, {0.f,0.f,0.f,0.f}, {0.f,0.f,0.f,0.f} };
#pragma unroll
        for (int kt = 0; kt < 4; ++kt) {
            bf16x8 pf;
#pragma unroll
            for (int j2 = 0; j2 < 4; ++j2) {
                const f32x2 e = sc2[kt][j2];
                pf[2 * j2 + 0] = (bf16_t)(e.x * rinv);
                pf[2 * j2 + 1] = (bf16_t)(e.y * rinv);
            }
#pragma unroll
            for (int ct = 0; ct < 4; ++ct)
                vacc[ct] = __builtin_amdgcn_mfma_f32_16x16x32_bf16(pf, xreg[kt][ct], vacc[ct], 0, 0, 0);
        }
        // V C-frags -> private wave scratch (intra-wave dep only, no barrier)
#pragma unroll
        for (int ct = 0; ct < 4; ++ct)
#pragma unroll
            for (int rr = 0; rr < 4; ++rr)
                Vscr[w][rq * 4 + rr][ct * 16 + cq] = (bf16_t)vacc[ct][rr];

        // ---- GEMM2: oacc += V[16x64] @ W_h[64x64] ----
#pragma unroll
        for (int kt = 0; kt < 2; ++kt) {
            const bf16x8 a = *(const bf16x8*)&Vscr[w][cq][kt * 32 + rq * 8];
#pragma unroll
            for (int ct = 0; ct < 4; ++ct) {
                const bf16x8 bw = *(const bf16x8*)&WTall[h * 4096 + (ct * 16 + cq) * 64 + (((kt * 4 + rq) ^ (cq & 7)) << 3)];
                oacc[ct] = __builtin_amdgcn_mfma_f32_16x16x32_bf16(a, bw, oacc[ct], 0, 0, 0);
            }
        }
    }

    // ---- epilogue: Out = oacc + bias (all 8 heads complete per wave) ----
#pragma unroll
    for (int ct = 0; ct < 4; ++ct) {
#pragma unroll
        for (int rr = 0; rr < 4; ++rr) {
            const int f = 16 * rt + rq * 4 + rr;
            const int o = ct * 16 + cq;
            Out[(((size_t)b * NF + f) * NT + t) * NDOUT + o] =
                oacc[ct][rr] + Bias[((size_t)f * NT + t) * NDOUT + o];
        }
    }
}

extern "C" void kernel_launch(void* const* d_in, const int* in_sizes, int n_in,
                              void* d_out, int out_size, void* d_ws, size_t ws_size,
                              hipStream_t stream) {
    (void)in_sizes; (void)n_in; (void)ws_size; (void)out_size;
    const float* X    = (const float*)d_in[0];
    const float* Wq   = (const float*)d_in[1];
    const float* Wk   = (const float*)d_in[2];
    const float* Wkey = (const float*)d_in[3];
    const float* U    = (const float*)d_in[4];
    const float* AC   = (const float*)d_in[5];
    const float* Al   = (const float*)d_in[6];
    // d_in[7] = R is analytic (delta^2, delta), folded into score formula
    const float* Wo   = (const float*)d_in[8];
    const float* Bias = (const float*)d_in[9];

    float* q_ws = (float*)d_ws;                       // 2 MB
    float* k_ws = q_ws + (size_t)NBS * NT * 16 * NF;  // 2 MB

    qk_project_kernel<<<dim3(NT * NF / 4), dim3(256), 0, stream>>>(X, Wq, Wk, q_ws, k_ws);
    spatial_attn_kernel<<<dim3(NBS * NT), dim3(512), 0, stream>>>(
        X, q_ws, k_ws, Wkey, U, AC, Al, Wo, Bias, (float*)d_out);
}